// Round 1
// baseline (221.975 us; speedup 1.0000x reference)
//
#include <hip/hip_runtime.h>

// AttnBlock: GroupNorm(4) -> q,k,v 1x1conv -> softmax(QK^T/16)V -> proj 1x1conv -> +x
// x: [4, 256, 64, 64] fp32, hw = 4096.
// All matmuls in bf16 MFMA (16x16x32), fp32 accumulate. fp32 softmax.

#define HW 4096
#define CCH 256
#define NBATCH 4
#define GN_N (64 * HW)   // elems per (batch, group): 64 ch * 4096

typedef unsigned short u16;
typedef __attribute__((ext_vector_type(8))) short bf16x8;
typedef __attribute__((ext_vector_type(4))) float f32x4;
typedef __attribute__((ext_vector_type(4))) u16 u16x4;

__device__ __forceinline__ u16 f2bf(float f) {
  unsigned u = __float_as_uint(f);
  u += 0x7fffu + ((u >> 16) & 1u);   // round-to-nearest-even
  return (u16)(u >> 16);
}

__device__ __forceinline__ void gload_lds16(const void* g, void* l) {
  __builtin_amdgcn_global_load_lds(
      (const __attribute__((address_space(1))) unsigned*)g,
      (__attribute__((address_space(3))) unsigned*)l, 16, 0, 0);
}

// ---------------- GroupNorm stats ----------------
// grid (32 blocks, 16 (b,g)); each block partial-reduces 8192 floats.
__global__ __launch_bounds__(256) void gn_partial(const float* __restrict__ x,
                                                  float* __restrict__ part) {
  const int bg = blockIdx.y, blk = blockIdx.x, tid = threadIdx.x;
  const float4* X = (const float4*)(x + (size_t)bg * GN_N);
  float s = 0.f, ss = 0.f;
#pragma unroll
  for (int u = 0; u < 8; ++u) {
    float4 v = X[blk * 2048 + u * 256 + tid];
    s += v.x + v.y + v.z + v.w;
    ss += v.x * v.x + v.y * v.y + v.z * v.z + v.w * v.w;
  }
  for (int off = 32; off; off >>= 1) { s += __shfl_xor(s, off); ss += __shfl_xor(ss, off); }
  __shared__ float rs[4], rss[4];
  const int w = tid >> 6;
  if ((tid & 63) == 0) { rs[w] = s; rss[w] = ss; }
  __syncthreads();
  if (tid == 0) {
    part[(bg * 32 + blk) * 2 + 0] = rs[0] + rs[1] + rs[2] + rs[3];
    part[(bg * 32 + blk) * 2 + 1] = rss[0] + rss[1] + rss[2] + rss[3];
  }
}

__global__ void gn_finalize(const float* __restrict__ part, float2* __restrict__ stats) {
  const int t = threadIdx.x;
  if (t < 16) {
    float s = 0.f, ss = 0.f;
    for (int u = 0; u < 32; ++u) { s += part[(t * 32 + u) * 2]; ss += part[(t * 32 + u) * 2 + 1]; }
    const float mean = s * (1.0f / GN_N);
    const float var = ss * (1.0f / GN_N) - mean * mean;
    stats[t] = make_float2(mean, rsqrtf(var + 1e-6f));
  }
}

// ---------------- normalize + transpose -> Ht[b][i][c] bf16 ----------------
// block handles a [64c x 64i] tile; grid (hw/64, c/64, b)
__global__ __launch_bounds__(256) void norm_tr(const float* __restrict__ x,
                                               const float2* __restrict__ stats,
                                               const float* __restrict__ gsc,
                                               const float* __restrict__ gbi,
                                               u16* __restrict__ Ht) {
  __shared__ u16 T[64][72];   // [i][c], padded
  const int i0 = blockIdx.x * 64, c0 = blockIdx.y * 64, b = blockIdx.z;
  const int tid = threadIdx.x;
  const int cl = tid >> 4;          // 0..15
  const int il4 = (tid & 15) * 4;   // 0..60
#pragma unroll
  for (int it = 0; it < 4; ++it) {
    const int c = c0 + it * 16 + cl;
    const float2 st = stats[b * 4 + (c >> 6)];
    const float sc = gsc[c] * st.y;
    const float bi = gbi[c] - st.x * sc;
    const float4 v = *(const float4*)&x[((size_t)(b * CCH + c)) * HW + i0 + il4];
    T[il4 + 0][it * 16 + cl] = f2bf(v.x * sc + bi);
    T[il4 + 1][it * 16 + cl] = f2bf(v.y * sc + bi);
    T[il4 + 2][it * 16 + cl] = f2bf(v.z * sc + bi);
    T[il4 + 3][it * 16 + cl] = f2bf(v.w * sc + bi);
  }
  __syncthreads();
  const int il = tid >> 2, cs = (tid & 3) * 16;
  const uint4 a = *(const uint4*)&T[il][cs];
  const uint4 b2 = *(const uint4*)&T[il][cs + 8];
  const size_t o = ((size_t)b * HW + i0 + il) * CCH + c0 + cs;
  *(uint4*)&Ht[o] = a;
  *(uint4*)&Ht[o + 8] = b2;
}

// ---------------- cast weights fp32 -> bf16 ----------------
__global__ __launch_bounds__(256) void wcast(const float* __restrict__ w0, const float* __restrict__ w1,
                                             const float* __restrict__ w2, const float* __restrict__ w3,
                                             u16* __restrict__ dst) {
  const float* src = blockIdx.y == 0 ? w0 : blockIdx.y == 1 ? w1 : blockIdx.y == 2 ? w2 : w3;
  u16* d = dst + (size_t)blockIdx.y * 65536;
  const int idx = (blockIdx.x * 256 + threadIdx.x) * 8;
  const float4 a = *(const float4*)&src[idx];
  const float4 c = *(const float4*)&src[idx + 4];
  uint4 p;
  p.x = (unsigned)f2bf(a.x) | ((unsigned)f2bf(a.y) << 16);
  p.y = (unsigned)f2bf(a.z) | ((unsigned)f2bf(a.w) << 16);
  p.z = (unsigned)f2bf(c.x) | ((unsigned)f2bf(c.y) << 16);
  p.w = (unsigned)f2bf(c.z) | ((unsigned)f2bf(c.w) << 16);
  *(uint4*)&d[idx] = p;
}

// ---------------- NT GEMM: Out[m][n] = scale * sum_k A[m][k]*B[n][k] (+bias[m]) ----------------
// A row-major [M][K] bf16, B col-major-as-[N][K] bf16.
// OMODE 0: bf16 row-major [M][N]; 1: bf16 transposed [N][M]; 2: fp32 [M][N] + bias + residual.
// 128x128 tile, BK=64, 4 waves, XOR-swizzled LDS (16B chunks ^ row&7), global_load_lds w16.
template <int OMODE, bool HASB>
__global__ __launch_bounds__(256) void gemm_nt(
    const u16* __restrict__ A, int lda, long sA,
    const u16* __restrict__ Bm, int ldb, long sB,
    void* __restrict__ OutP, int ldo, long sO,
    const float* __restrict__ bias,
    const float* __restrict__ res, long sR,
    float scale, int K) {
  __shared__ u16 lsA[128 * 64];
  __shared__ u16 lsB[128 * 64];
  const int tid = threadIdx.x;
  const int z = blockIdx.z;
  const int m0 = blockIdx.y * 128;
  const int n0 = blockIdx.x * 128;
  const u16* Ab = A + (size_t)z * sA;
  const u16* Bb = Bm + (size_t)z * sB;
  const int w = tid >> 6, l = tid & 63;
  const int wm = w >> 1, wn = w & 1;   // 2x2 waves, each 64x64
  f32x4 acc[4][4];
#pragma unroll
  for (int i = 0; i < 4; ++i)
#pragma unroll
    for (int j = 0; j < 4; ++j)
#pragma unroll
      for (int q = 0; q < 4; ++q) acc[i][j][q] = 0.f;

  for (int k0 = 0; k0 < K; k0 += 64) {
#pragma unroll
    for (int s = 0; s < 4; ++s) {
      const int o = s * 4096 + tid * 16;          // byte offset in 16KB tile
      const int r = o >> 7;                       // row 0..127
      const int c = ((o >> 4) & 7) ^ (r & 7);     // logical 16B chunk (swizzle inverse)
      const int ke = c * 8;                       // k element offset
      gload_lds16(Ab + (size_t)(m0 + r) * lda + k0 + ke, (char*)lsA + s * 4096 + w * 1024);
      gload_lds16(Bb + (size_t)(n0 + r) * ldb + k0 + ke, (char*)lsB + s * 4096 + w * 1024);
    }
    asm volatile("s_waitcnt vmcnt(0)" ::: "memory");
    __syncthreads();
#pragma unroll
    for (int kk = 0; kk < 2; ++kk) {
      bf16x8 aF[4], bF[4];
#pragma unroll
      for (int mi = 0; mi < 4; ++mi) {
        const int r = wm * 64 + mi * 16 + (l & 15);
        const int cc = (kk * 4 + (l >> 4)) ^ (r & 7);
        aF[mi] = *(const bf16x8*)((const char*)lsA + r * 128 + cc * 16);
      }
#pragma unroll
      for (int ni = 0; ni < 4; ++ni) {
        const int r = wn * 64 + ni * 16 + (l & 15);
        const int cc = (kk * 4 + (l >> 4)) ^ (r & 7);
        bF[ni] = *(const bf16x8*)((const char*)lsB + r * 128 + cc * 16);
      }
#pragma unroll
      for (int mi = 0; mi < 4; ++mi)
#pragma unroll
        for (int ni = 0; ni < 4; ++ni)
          acc[mi][ni] = __builtin_amdgcn_mfma_f32_16x16x32_bf16(aF[mi], bF[ni], acc[mi][ni], 0, 0, 0);
    }
    __syncthreads();
  }

  const int lc = l & 15;
  const int lr4 = (l >> 4) * 4;   // C/D: col=lane&15, row=(lane>>4)*4+reg  [guide-verified]
#pragma unroll
  for (int mi = 0; mi < 4; ++mi) {
    const int mb = m0 + wm * 64 + mi * 16 + lr4;
    float b4[4] = {0.f, 0.f, 0.f, 0.f};
    if (HASB) {
      const float4 bv = *(const float4*)&bias[mb];
      b4[0] = bv.x; b4[1] = bv.y; b4[2] = bv.z; b4[3] = bv.w;
    }
#pragma unroll
    for (int ni = 0; ni < 4; ++ni) {
      const int n = n0 + wn * 64 + ni * 16 + lc;
      if (OMODE == 0) {
        u16* O = (u16*)OutP + (size_t)z * sO;
#pragma unroll
        for (int q = 0; q < 4; ++q)
          O[(size_t)(mb + q) * ldo + n] = f2bf(acc[mi][ni][q] * scale + b4[q]);
      } else if (OMODE == 1) {
        u16* O = (u16*)OutP + (size_t)z * sO;
        u16x4 pk;
#pragma unroll
        for (int q = 0; q < 4; ++q) pk[q] = f2bf(acc[mi][ni][q] * scale + b4[q]);
        *(u16x4*)&O[(size_t)n * ldo + mb] = pk;
      } else {
        float* O = (float*)OutP + (size_t)z * sO;
        const float* R = res + (size_t)z * sR;
#pragma unroll
        for (int q = 0; q < 4; ++q)
          O[(size_t)(mb + q) * ldo + n] = acc[mi][ni][q] * scale + b4[q] + R[(size_t)(mb + q) * ldo + n];
      }
    }
  }
}

// ---------------- fused one-pass row softmax, in place on bf16 S ----------------
__global__ __launch_bounds__(256) void softmax_rows(u16* __restrict__ S) {
  const size_t rowoff = (size_t)blockIdx.y * ((size_t)HW * HW) + (size_t)blockIdx.x * HW;
  u16* row = S + rowoff;
  const int tid = threadIdx.x;
  uint4 d0 = *(const uint4*)&row[tid * 16];
  uint4 d1 = *(const uint4*)&row[tid * 16 + 8];
  unsigned uu[8] = {d0.x, d0.y, d0.z, d0.w, d1.x, d1.y, d1.z, d1.w};
  float v[16];
#pragma unroll
  for (int j = 0; j < 8; ++j) {
    v[2 * j] = __uint_as_float(uu[j] << 16);
    v[2 * j + 1] = __uint_as_float(uu[j] & 0xffff0000u);
  }
  float m = v[0];
#pragma unroll
  for (int j = 1; j < 16; ++j) m = fmaxf(m, v[j]);
  for (int off = 32; off; off >>= 1) m = fmaxf(m, __shfl_xor(m, off));
  __shared__ float red[8];
  if ((tid & 63) == 0) red[tid >> 6] = m;
  __syncthreads();
  m = fmaxf(fmaxf(red[0], red[1]), fmaxf(red[2], red[3]));
  float ssum = 0.f;
#pragma unroll
  for (int j = 0; j < 16; ++j) { v[j] = __expf(v[j] - m); ssum += v[j]; }
  for (int off = 32; off; off >>= 1) ssum += __shfl_xor(ssum, off);
  if ((tid & 63) == 0) red[4 + (tid >> 6)] = ssum;
  __syncthreads();
  ssum = red[4] + red[5] + red[6] + red[7];
  const float inv = 1.f / ssum;
#pragma unroll
  for (int j = 0; j < 8; ++j) {
    const unsigned lo = f2bf(v[2 * j] * inv), hi = f2bf(v[2 * j + 1] * inv);
    uu[j] = lo | (hi << 16);
  }
  *(uint4*)&row[tid * 16] = make_uint4(uu[0], uu[1], uu[2], uu[3]);
  *(uint4*)&row[tid * 16 + 8] = make_uint4(uu[4], uu[5], uu[6], uu[7]);
}

extern "C" void kernel_launch(void* const* d_in, const int* in_sizes, int n_in,
                              void* d_out, int out_size, void* d_ws, size_t ws_size,
                              hipStream_t stream) {
  const float* x   = (const float*)d_in[0];
  const float* gsc = (const float*)d_in[1];
  const float* gbi = (const float*)d_in[2];
  const float* wq  = (const float*)d_in[3];
  const float* bq  = (const float*)d_in[4];
  const float* wk  = (const float*)d_in[5];
  const float* bk  = (const float*)d_in[6];
  const float* wv  = (const float*)d_in[7];
  const float* bv  = (const float*)d_in[8];
  const float* wp  = (const float*)d_in[9];
  const float* bp  = (const float*)d_in[10];
  float* out = (float*)d_out;

  char* ws = (char*)d_ws;
  size_t off = 0;
  auto alloc = [&](size_t bytes) {
    size_t o = off; off = (off + bytes + 255) & ~(size_t)255; return o;
  };
  const size_t szMat = (size_t)NBATCH * HW * CCH * 2;  // 8.4MB bf16
  u16* W      = (u16*)(ws + alloc(4 * 65536 * 2));     // Wq,Wk,Wv,Wp bf16
  float* part = (float*)(ws + alloc(16 * 32 * 2 * 4));
  float2* st  = (float2*)(ws + alloc(16 * 8));
  u16* Ht = (u16*)(ws + alloc(szMat));   // [b][i][c]
  u16* Qt = (u16*)(ws + alloc(szMat));   // [b][i][c]
  u16* Kt = (u16*)(ws + alloc(szMat));   // [b][j][c]
  u16* Vv = (u16*)(ws + alloc(szMat));   // [b][c][j]
  u16* Ot = (u16*)(ws + alloc(szMat));   // [b][i][c]
  const size_t szS1 = (size_t)HW * HW * 2;             // 33.5MB per batch
  const bool batched = (off + (size_t)NBATCH * szS1) <= ws_size;
  u16* S = (u16*)(ws + off);                           // batched: 134MB, else 33.5MB reused

  wcast<<<dim3(32, 4), 256, 0, stream>>>(wq, wk, wv, wp, W);
  gn_partial<<<dim3(32, 16), 256, 0, stream>>>(x, part);
  gn_finalize<<<1, 64, 0, stream>>>(part, st);
  norm_tr<<<dim3(HW / 64, CCH / 64, NBATCH), 256, 0, stream>>>(x, st, gsc, gbi, Ht);

  const long sM = (long)HW * CCH;
  // Q/K transposed [i][c]; V row-major [c][j]
  gemm_nt<1, true><<<dim3(32, 2, NBATCH), 256, 0, stream>>>(W, 256, 0, Ht, 256, sM, Qt, 256, sM, bq, nullptr, 0, 1.f, 256);
  gemm_nt<1, true><<<dim3(32, 2, NBATCH), 256, 0, stream>>>(W + 65536, 256, 0, Ht, 256, sM, Kt, 256, sM, bk, nullptr, 0, 1.f, 256);
  gemm_nt<0, true><<<dim3(32, 2, NBATCH), 256, 0, stream>>>(W + 2 * 65536, 256, 0, Ht, 256, sM, Vv, HW, sM, bv, nullptr, 0, 1.f, 256);

  const int zdim = batched ? NBATCH : 1;
  const int nit = batched ? 1 : NBATCH;
  const long sS = (long)HW * HW;
  for (int bb = 0; bb < nit; ++bb) {
    const size_t mo = (size_t)bb * HW * CCH;
    // S[i][j] = (Qt . Kt^T) / 16, bf16
    gemm_nt<0, false><<<dim3(32, 32, zdim), 256, 0, stream>>>(Qt + mo, 256, sM, Kt + mo, 256, sM, S, HW, sS, nullptr, nullptr, 0, 0.0625f, 256);
    softmax_rows<<<dim3(HW, zdim), 256, 0, stream>>>(S);
    // Ot[i][c] = sum_j V[c][j] P[i][j]
    gemm_nt<1, false><<<dim3(32, 2, zdim), 256, 0, stream>>>(Vv + mo, HW, sM, S, HW, sS, Ot + mo, 256, sM, nullptr, nullptr, 0, 1.f, HW);
  }
  // out[c][i] = Wp . Ot^T + bp + x   (fp32)
  gemm_nt<2, true><<<dim3(32, 2, NBATCH), 256, 0, stream>>>(W + 3 * 65536, 256, 0, Ot, 256, sM, out, HW, (long)CCH * HW, bp, x, (long)CCH * HW, 1.f, 256);
}

// Round 2
// 209.361 us; speedup vs baseline: 1.0603x; 1.0603x over previous
//
#include <hip/hip_runtime.h>

// AttnBlock: GroupNorm(4) -> fused qkv 1x1conv -> P'=exp(QK^T/16-8) + row-sums
//            -> PV (pure GEMM, invl epilogue) -> proj 1x1conv + residual
// All GEMMs: bf16 MFMA 16x16x32, 128x128 tile, BK=64, 2-phase dbuf LDS,
// XOR-swizzled LDS, global_load_lds w16, XCD-chunked block swizzle.

#define HW 4096
#define CCH 256
#define NBATCH 4
#define GN_N (64 * HW)

typedef unsigned short u16;
typedef __attribute__((ext_vector_type(8))) short bf16x8;
typedef __attribute__((ext_vector_type(4))) float f32x4;
typedef __attribute__((ext_vector_type(4))) u16 u16x4;

__device__ __forceinline__ u16 f2bf(float f) {
  unsigned u = __float_as_uint(f);
  u += 0x7fffu + ((u >> 16) & 1u);   // round-to-nearest-even
  return (u16)(u >> 16);
}
__device__ __forceinline__ float bf2f(u16 h) { return __uint_as_float(((unsigned)h) << 16); }

__device__ __forceinline__ void gload_lds16(const void* g, void* l) {
  __builtin_amdgcn_global_load_lds(
      (const __attribute__((address_space(1))) unsigned*)g,
      (__attribute__((address_space(3))) unsigned*)l, 16, 0, 0);
}

// ---------------- GroupNorm stats ----------------
__global__ __launch_bounds__(256) void gn_partial(const float* __restrict__ x,
                                                  float* __restrict__ part) {
  const int bg = blockIdx.y, blk = blockIdx.x, tid = threadIdx.x;
  const float4* X = (const float4*)(x + (size_t)bg * GN_N);
  float s = 0.f, ss = 0.f;
#pragma unroll
  for (int u = 0; u < 8; ++u) {
    float4 v = X[blk * 2048 + u * 256 + tid];
    s += v.x + v.y + v.z + v.w;
    ss += v.x * v.x + v.y * v.y + v.z * v.z + v.w * v.w;
  }
  for (int off = 32; off; off >>= 1) { s += __shfl_xor(s, off); ss += __shfl_xor(ss, off); }
  __shared__ float rs[4], rss[4];
  const int w = tid >> 6;
  if ((tid & 63) == 0) { rs[w] = s; rss[w] = ss; }
  __syncthreads();
  if (tid == 0) {
    part[(bg * 32 + blk) * 2 + 0] = rs[0] + rs[1] + rs[2] + rs[3];
    part[(bg * 32 + blk) * 2 + 1] = rss[0] + rss[1] + rss[2] + rss[3];
  }
}

__global__ void gn_finalize(const float* __restrict__ part, float2* __restrict__ stats) {
  const int t = threadIdx.x;
  if (t < 16) {
    float s = 0.f, ss = 0.f;
    for (int u = 0; u < 32; ++u) { s += part[(t * 32 + u) * 2]; ss += part[(t * 32 + u) * 2 + 1]; }
    const float mean = s * (1.0f / GN_N);
    const float var = ss * (1.0f / GN_N) - mean * mean;
    stats[t] = make_float2(mean, rsqrtf(var + 1e-6f));
  }
}

// ---------------- normalize + transpose -> Ht[b][i][c] bf16 ----------------
__global__ __launch_bounds__(256) void norm_tr(const float* __restrict__ x,
                                               const float2* __restrict__ stats,
                                               const float* __restrict__ gsc,
                                               const float* __restrict__ gbi,
                                               u16* __restrict__ Ht) {
  __shared__ u16 T[64][72];
  const int i0 = blockIdx.x * 64, c0 = blockIdx.y * 64, b = blockIdx.z;
  const int tid = threadIdx.x;
  const int cl = tid >> 4;
  const int il4 = (tid & 15) * 4;
#pragma unroll
  for (int it = 0; it < 4; ++it) {
    const int c = c0 + it * 16 + cl;
    const float2 st = stats[b * 4 + (c >> 6)];
    const float sc = gsc[c] * st.y;
    const float bi = gbi[c] - st.x * sc;
    const float4 v = *(const float4*)&x[((size_t)(b * CCH + c)) * HW + i0 + il4];
    T[il4 + 0][it * 16 + cl] = f2bf(v.x * sc + bi);
    T[il4 + 1][it * 16 + cl] = f2bf(v.y * sc + bi);
    T[il4 + 2][it * 16 + cl] = f2bf(v.z * sc + bi);
    T[il4 + 3][it * 16 + cl] = f2bf(v.w * sc + bi);
  }
  __syncthreads();
  const int il = tid >> 2, cs = (tid & 3) * 16;
  const uint4 a = *(const uint4*)&T[il][cs];
  const uint4 b2 = *(const uint4*)&T[il][cs + 8];
  const size_t o = ((size_t)b * HW + i0 + il) * CCH + c0 + cs;
  *(uint4*)&Ht[o] = a;
  *(uint4*)&Ht[o + 8] = b2;
}

// ---------------- cast weights fp32 -> bf16 ----------------
__global__ __launch_bounds__(256) void wcast(const float* __restrict__ w0, const float* __restrict__ w1,
                                             const float* __restrict__ w2, const float* __restrict__ w3,
                                             u16* __restrict__ dst) {
  const float* src = blockIdx.y == 0 ? w0 : blockIdx.y == 1 ? w1 : blockIdx.y == 2 ? w2 : w3;
  u16* d = dst + (size_t)blockIdx.y * 65536;
  const int idx = (blockIdx.x * 256 + threadIdx.x) * 8;
  const float4 a = *(const float4*)&src[idx];
  const float4 c = *(const float4*)&src[idx + 4];
  uint4 p;
  p.x = (unsigned)f2bf(a.x) | ((unsigned)f2bf(a.y) << 16);
  p.y = (unsigned)f2bf(a.z) | ((unsigned)f2bf(a.w) << 16);
  p.z = (unsigned)f2bf(c.x) | ((unsigned)f2bf(c.y) << 16);
  p.w = (unsigned)f2bf(c.z) | ((unsigned)f2bf(c.w) << 16);
  *(uint4*)&d[idx] = p;
}

// ---------------- NT GEMM, 2-phase double-buffered pipeline ----------------
// Out[m][n] = scale*sum_k A[m][k]*B[n][k] (+ epilogue)
// EPI 2: fp32 [m][n] + bias + residual(aux)
// EPI 3: P' = exp(acc*scale - 8) bf16 [m][n]; row partial sums -> auxw[(bz*64+nb)*HW + row]
// EPI 4: bf16 [m][n] scaled by aux(invl)[bz*HW + m]
// EPI 5: fused QKV: m0<512 -> transposed bf16 (O0=Qt / O1=Kt), m0>=512 -> row-major Vv (O2)
template <int EPI, bool HASB>
__global__ __launch_bounds__(256) void gemm2(
    const u16* __restrict__ A, int lda, long sA,
    const u16* __restrict__ Bm, int ldb, long sB,
    void* __restrict__ O0, int ldo, long sO,
    void* __restrict__ O1, void* __restrict__ O2,
    const float* __restrict__ b0, const float* __restrict__ b1, const float* __restrict__ b2,
    const float* __restrict__ aux, float* __restrict__ auxw, long sAux,
    float scale, int K) {
  __shared__ char lsA[32768], lsB[32768];   // 2 buf x 16KB each
  int bx, by, bz;
  {
    const int nx = gridDim.x, ny = gridDim.y;
    const int lin = blockIdx.x + nx * (blockIdx.y + ny * blockIdx.z);
    const int q = (nx * ny * (int)gridDim.z) >> 3;   // nwg % 8 == 0 for all grids here
    const int wg = (lin & 7) * q + (lin >> 3);
    bx = wg % nx; const int t2 = wg / nx; by = t2 % ny; bz = t2 / ny;
  }
  const int tid = threadIdx.x;
  const int w = tid >> 6, l = tid & 63;
  const int wm = w >> 1, wn = w & 1;
  const int m0 = by * 128, n0 = bx * 128;
  const u16* Ab = A + (size_t)bz * sA;
  const u16* Bb = Bm + (size_t)bz * sB;

  f32x4 acc[4][4];
#pragma unroll
  for (int i = 0; i < 4; ++i)
#pragma unroll
    for (int j = 0; j < 4; ++j)
#pragma unroll
      for (int q2 = 0; q2 < 4; ++q2) acc[i][j][q2] = 0.f;

  auto stage = [&](int buf, int k0) {
#pragma unroll
    for (int s = 0; s < 4; ++s) {
      const int o = s * 4096 + tid * 16;
      const int r = o >> 7;
      const int c = ((o >> 4) & 7) ^ (r & 7);
      const int ke = c * 8;
      gload_lds16(Ab + (size_t)(m0 + r) * lda + k0 + ke, lsA + buf * 16384 + s * 4096 + w * 1024);
      gload_lds16(Bb + (size_t)(n0 + r) * ldb + k0 + ke, lsB + buf * 16384 + s * 4096 + w * 1024);
    }
  };

  const int nt = K >> 6;
  stage(0, 0);
  asm volatile("s_waitcnt vmcnt(0)" ::: "memory");
  __syncthreads();
  for (int t = 0; t < nt; ++t) {
    const int cur = t & 1;
    if (t + 1 < nt) stage(cur ^ 1, (t + 1) << 6);
#pragma unroll
    for (int kk = 0; kk < 2; ++kk) {
      bf16x8 aF[4], bF[4];
#pragma unroll
      for (int mi = 0; mi < 4; ++mi) {
        const int r = wm * 64 + mi * 16 + (l & 15);
        const int cc = (kk * 4 + (l >> 4)) ^ (r & 7);
        aF[mi] = *(const bf16x8*)(lsA + cur * 16384 + r * 128 + cc * 16);
      }
#pragma unroll
      for (int ni = 0; ni < 4; ++ni) {
        const int r = wn * 64 + ni * 16 + (l & 15);
        const int cc = (kk * 4 + (l >> 4)) ^ (r & 7);
        bF[ni] = *(const bf16x8*)(lsB + cur * 16384 + r * 128 + cc * 16);
      }
#pragma unroll
      for (int mi = 0; mi < 4; ++mi)
#pragma unroll
        for (int ni = 0; ni < 4; ++ni)
          acc[mi][ni] = __builtin_amdgcn_mfma_f32_16x16x32_bf16(aF[mi], bF[ni], acc[mi][ni], 0, 0, 0);
    }
    asm volatile("s_waitcnt vmcnt(0)" ::: "memory");
    __syncthreads();
  }

  const int lc = l & 15;
  const int lr4 = (l >> 4) * 4;   // C/D: col=lane&15, row=(lane>>4)*4+reg

  if (EPI == 5) {
    const int sel = m0 >> 8;   // 0:Q 1:K 2:V (128-tiles are 256-aligned within the 768 stack)
    const float* bs = sel == 0 ? b0 : sel == 1 ? b1 : b2;
#pragma unroll
    for (int mi = 0; mi < 4; ++mi) {
      const int mg = m0 + wm * 64 + mi * 16 + lr4;
      const int mloc = mg & 255;
      const float4 bv = *(const float4*)&bs[mloc];
      float bb4[4] = {bv.x, bv.y, bv.z, bv.w};
#pragma unroll
      for (int ni = 0; ni < 4; ++ni) {
        const int n = n0 + wn * 64 + ni * 16 + lc;
        if (sel == 2) {
          u16* V = (u16*)O2 + (size_t)bz * sO;
#pragma unroll
          for (int q2 = 0; q2 < 4; ++q2) V[(size_t)(mloc + q2) * HW + n] = f2bf(acc[mi][ni][q2] + bb4[q2]);
        } else {
          u16* Oq = (u16*)(sel == 0 ? O0 : O1) + (size_t)bz * sO;
          u16x4 pk;
#pragma unroll
          for (int q2 = 0; q2 < 4; ++q2) pk[q2] = f2bf(acc[mi][ni][q2] + bb4[q2]);
          *(u16x4*)&Oq[(size_t)n * CCH + mloc] = pk;
        }
      }
    }
  } else if (EPI == 3) {
    u16* O = (u16*)O0 + (size_t)bz * sO;
    const int nb = (n0 >> 6) + wn;
#pragma unroll
    for (int mi = 0; mi < 4; ++mi) {
      const int mb = m0 + wm * 64 + mi * 16 + lr4;
      float rs[4] = {0.f, 0.f, 0.f, 0.f};
#pragma unroll
      for (int ni = 0; ni < 4; ++ni) {
        const int n = n0 + wn * 64 + ni * 16 + lc;
#pragma unroll
        for (int q2 = 0; q2 < 4; ++q2) {
          const u16 pb = f2bf(__expf(acc[mi][ni][q2] * scale - 8.0f));
          O[(size_t)(mb + q2) * ldo + n] = pb;
          rs[q2] += bf2f(pb);
        }
      }
#pragma unroll
      for (int q2 = 0; q2 < 4; ++q2) {
        rs[q2] += __shfl_xor(rs[q2], 1);
        rs[q2] += __shfl_xor(rs[q2], 2);
        rs[q2] += __shfl_xor(rs[q2], 4);
        rs[q2] += __shfl_xor(rs[q2], 8);
      }
      if ((l & 15) == 0)
        *(float4*)&auxw[((size_t)bz * 64 + nb) * HW + mb] = make_float4(rs[0], rs[1], rs[2], rs[3]);
    }
  } else if (EPI == 4) {
    u16* O = (u16*)O0 + (size_t)bz * sO;
    const float* invl = aux + (size_t)bz * HW;
#pragma unroll
    for (int mi = 0; mi < 4; ++mi) {
      const int mb = m0 + wm * 64 + mi * 16 + lr4;
      const float4 iv = *(const float4*)&invl[mb];
      float v4[4] = {iv.x, iv.y, iv.z, iv.w};
#pragma unroll
      for (int ni = 0; ni < 4; ++ni) {
        const int n = n0 + wn * 64 + ni * 16 + lc;
#pragma unroll
        for (int q2 = 0; q2 < 4; ++q2)
          O[(size_t)(mb + q2) * ldo + n] = f2bf(acc[mi][ni][q2] * v4[q2]);
      }
    }
  } else {   // EPI == 2
    float* O = (float*)O0 + (size_t)bz * sO;
    const float* R = aux + (size_t)bz * sAux;
#pragma unroll
    for (int mi = 0; mi < 4; ++mi) {
      const int mb = m0 + wm * 64 + mi * 16 + lr4;
      float bb4[4] = {0.f, 0.f, 0.f, 0.f};
      if (HASB) {
        const float4 bv = *(const float4*)&b0[mb];
        bb4[0] = bv.x; bb4[1] = bv.y; bb4[2] = bv.z; bb4[3] = bv.w;
      }
#pragma unroll
      for (int ni = 0; ni < 4; ++ni) {
        const int n = n0 + wn * 64 + ni * 16 + lc;
#pragma unroll
        for (int q2 = 0; q2 < 4; ++q2)
          O[(size_t)(mb + q2) * ldo + n] = acc[mi][ni][q2] * scale + bb4[q2] + R[(size_t)(mb + q2) * ldo + n];
      }
    }
  }
}

// ---------------- softmax-denominator combine: invl[r] = 1 / sum_nb part ----------------
__global__ __launch_bounds__(256) void sm_combine(const float* __restrict__ part, float* __restrict__ invl) {
  const int r = blockIdx.x * 256 + threadIdx.x;   // 0..16383 = z*HW + i
  const int z = r >> 12;
  const int i = r & 4095;
  const float* p = part + (size_t)z * 64 * HW + i;
  float s = 0.f;
#pragma unroll
  for (int nb = 0; nb < 64; ++nb) s += p[(size_t)nb * HW];
  invl[r] = 1.0f / s;
}

extern "C" void kernel_launch(void* const* d_in, const int* in_sizes, int n_in,
                              void* d_out, int out_size, void* d_ws, size_t ws_size,
                              hipStream_t stream) {
  const float* x   = (const float*)d_in[0];
  const float* gsc = (const float*)d_in[1];
  const float* gbi = (const float*)d_in[2];
  const float* wq  = (const float*)d_in[3];
  const float* bq  = (const float*)d_in[4];
  const float* wk  = (const float*)d_in[5];
  const float* bk  = (const float*)d_in[6];
  const float* wv  = (const float*)d_in[7];
  const float* bv  = (const float*)d_in[8];
  const float* wp  = (const float*)d_in[9];
  const float* bp  = (const float*)d_in[10];
  float* out = (float*)d_out;

  char* ws = (char*)d_ws;
  size_t off = 0;
  auto alloc = [&](size_t bytes) {
    size_t o = off; off = (off + bytes + 255) & ~(size_t)255; return o;
  };
  const size_t szMat = (size_t)NBATCH * HW * CCH * 2;   // 8.4MB
  u16* W      = (u16*)(ws + alloc(4 * 65536 * 2));
  float* pgn  = (float*)(ws + alloc(16 * 32 * 2 * 4));
  float2* st  = (float2*)(ws + alloc(16 * 8));
  u16* Ht = (u16*)(ws + alloc(szMat));   // [b][i][c]; dead after QKV -> reused for softmax stats
  u16* Qt = (u16*)(ws + alloc(szMat));   // [b][i][c]
  u16* Kt = (u16*)(ws + alloc(szMat));   // [b][j][c]
  u16* Vv = (u16*)(ws + alloc(szMat));   // [b][c][j]
  u16* Ot = (u16*)(ws + alloc(szMat));   // [b][i][c]
  u16* P  = (u16*)(ws + alloc((size_t)NBATCH * HW * HW * 2));   // 134MB, P' = exp(s-8)
  float* smpart = (float*)Ht;                                    // [b][64][HW] = 4MB (aliases dead Ht)
  float* invl   = (float*)((char*)Ht + 4 * 1024 * 1024 + 256);   // [b][HW] = 64KB

  const long sM = (long)HW * CCH;
  const long sS = (long)HW * HW;

  wcast<<<dim3(32, 4), 256, 0, stream>>>(wq, wk, wv, wp, W);
  gn_partial<<<dim3(32, 16), 256, 0, stream>>>(x, pgn);
  gn_finalize<<<1, 64, 0, stream>>>(pgn, st);
  norm_tr<<<dim3(HW / 64, CCH / 64, NBATCH), 256, 0, stream>>>(x, st, gsc, gbi, Ht);

  // fused QKV: A = [Wq;Wk;Wv] (768x256), B = Ht -> Qt [i][c], Kt [j][c], Vv [c][j]
  gemm2<5, true><<<dim3(32, 6, NBATCH), 256, 0, stream>>>(
      W, 256, 0, Ht, 256, sM, Qt, 256, sM, Kt, Vv, bq, bk, bv, nullptr, nullptr, 0, 1.f, 256);

  // P'[i][j] = exp(q.k/16 - 8) bf16 + row partial sums
  gemm2<3, false><<<dim3(32, 32, NBATCH), 256, 0, stream>>>(
      Qt, 256, sM, Kt, 256, sM, P, HW, sS, nullptr, nullptr, nullptr, nullptr, nullptr,
      nullptr, smpart, 0, 0.0625f, 256);

  sm_combine<<<64, 256, 0, stream>>>(smpart, invl);

  // Ot[i][c] = invl[i] * sum_j P'[i][j] * V[c][j]   (pure GEMM + scale epilogue)
  gemm2<4, false><<<dim3(2, 32, NBATCH), 256, 0, stream>>>(
      P, HW, sS, Vv, HW, sM, Ot, 256, sM, nullptr, nullptr, nullptr, nullptr, nullptr,
      invl, nullptr, 0, 1.f, HW);

  // out[c][i] = Wp . Ot^T + bp + x
  gemm2<2, true><<<dim3(32, 2, NBATCH), 256, 0, stream>>>(
      W + 3 * 65536, 256, 0, Ot, 256, sM, out, HW, (long)CCH * HW, nullptr, nullptr,
      bp, nullptr, nullptr, x, nullptr, (long)CCH * HW, 1.f, 256);
}

// Round 4
// 198.458 us; speedup vs baseline: 1.1185x; 1.0549x over previous
//
#include <hip/hip_runtime.h>

// AttnBlock: GroupNorm(4) -> fused qkv 1x1conv -> FUSED flash attention
//            (S^T via mfma(K,Q), exp(s/16-8), P relayout via per-wave LDS, PV)
//            -> combine (j-split merge + 1/l scale) -> proj 1x1conv + residual
// bf16 MFMA 16x16x32 everywhere, fp32 accumulate.

#define HW 4096
#define CCH 256
#define NBATCH 4
#define GN_N (64 * HW)

typedef unsigned short u16;
typedef __attribute__((ext_vector_type(8))) short bf16x8;
typedef __attribute__((ext_vector_type(4))) float f32x4;
typedef __attribute__((ext_vector_type(4))) u16 u16x4;

__device__ __forceinline__ u16 f2bf(float f) {
  unsigned u = __float_as_uint(f);
  u += 0x7fffu + ((u >> 16) & 1u);   // round-to-nearest-even
  return (u16)(u >> 16);
}
__device__ __forceinline__ float bf2f(u16 h) { return __uint_as_float(((unsigned)h) << 16); }

__device__ __forceinline__ void gload_lds16(const void* g, void* l) {
  __builtin_amdgcn_global_load_lds(
      (const __attribute__((address_space(1))) unsigned*)g,
      (__attribute__((address_space(3))) unsigned*)l, 16, 0, 0);
}

// ---------------- GroupNorm stats ----------------
__global__ __launch_bounds__(256) void gn_partial(const float* __restrict__ x,
                                                  float* __restrict__ part) {
  const int bg = blockIdx.y, blk = blockIdx.x, tid = threadIdx.x;
  const float4* X = (const float4*)(x + (size_t)bg * GN_N);
  float s = 0.f, ss = 0.f;
#pragma unroll
  for (int u = 0; u < 8; ++u) {
    float4 v = X[blk * 2048 + u * 256 + tid];
    s += v.x + v.y + v.z + v.w;
    ss += v.x * v.x + v.y * v.y + v.z * v.z + v.w * v.w;
  }
  for (int off = 32; off; off >>= 1) { s += __shfl_xor(s, off); ss += __shfl_xor(ss, off); }
  __shared__ float rs[4], rss[4];
  const int w = tid >> 6;
  if ((tid & 63) == 0) { rs[w] = s; rss[w] = ss; }
  __syncthreads();
  if (tid == 0) {
    part[(bg * 32 + blk) * 2 + 0] = rs[0] + rs[1] + rs[2] + rs[3];
    part[(bg * 32 + blk) * 2 + 1] = rss[0] + rss[1] + rss[2] + rss[3];
  }
}

__global__ void gn_finalize(const float* __restrict__ part, float2* __restrict__ stats) {
  const int t = threadIdx.x;
  if (t < 16) {
    float s = 0.f, ss = 0.f;
    for (int u = 0; u < 32; ++u) { s += part[(t * 32 + u) * 2]; ss += part[(t * 32 + u) * 2 + 1]; }
    const float mean = s * (1.0f / GN_N);
    const float var = ss * (1.0f / GN_N) - mean * mean;
    stats[t] = make_float2(mean, rsqrtf(var + 1e-6f));
  }
}

// ---------------- normalize + transpose -> Ht[b][i][c] bf16 ----------------
__global__ __launch_bounds__(256) void norm_tr(const float* __restrict__ x,
                                               const float2* __restrict__ stats,
                                               const float* __restrict__ gsc,
                                               const float* __restrict__ gbi,
                                               u16* __restrict__ Ht) {
  __shared__ u16 T[64][72];
  const int i0 = blockIdx.x * 64, c0 = blockIdx.y * 64, b = blockIdx.z;
  const int tid = threadIdx.x;
  const int cl = tid >> 4;
  const int il4 = (tid & 15) * 4;
#pragma unroll
  for (int it = 0; it < 4; ++it) {
    const int c = c0 + it * 16 + cl;
    const float2 st = stats[b * 4 + (c >> 6)];
    const float sc = gsc[c] * st.y;
    const float bi = gbi[c] - st.x * sc;
    const float4 v = *(const float4*)&x[((size_t)(b * CCH + c)) * HW + i0 + il4];
    T[il4 + 0][it * 16 + cl] = f2bf(v.x * sc + bi);
    T[il4 + 1][it * 16 + cl] = f2bf(v.y * sc + bi);
    T[il4 + 2][it * 16 + cl] = f2bf(v.z * sc + bi);
    T[il4 + 3][it * 16 + cl] = f2bf(v.w * sc + bi);
  }
  __syncthreads();
  const int il = tid >> 2, cs = (tid & 3) * 16;
  const uint4 a = *(const uint4*)&T[il][cs];
  const uint4 b2 = *(const uint4*)&T[il][cs + 8];
  const size_t o = ((size_t)b * HW + i0 + il) * CCH + c0 + cs;
  *(uint4*)&Ht[o] = a;
  *(uint4*)&Ht[o + 8] = b2;
}

// ---------------- cast weights fp32 -> bf16 ----------------
__global__ __launch_bounds__(256) void wcast(const float* __restrict__ w0, const float* __restrict__ w1,
                                             const float* __restrict__ w2, const float* __restrict__ w3,
                                             u16* __restrict__ dst) {
  const float* src = blockIdx.y == 0 ? w0 : blockIdx.y == 1 ? w1 : blockIdx.y == 2 ? w2 : w3;
  u16* d = dst + (size_t)blockIdx.y * 65536;
  const int idx = (blockIdx.x * 256 + threadIdx.x) * 8;
  const float4 a = *(const float4*)&src[idx];
  const float4 c = *(const float4*)&src[idx + 4];
  uint4 p;
  p.x = (unsigned)f2bf(a.x) | ((unsigned)f2bf(a.y) << 16);
  p.y = (unsigned)f2bf(a.z) | ((unsigned)f2bf(a.w) << 16);
  p.z = (unsigned)f2bf(c.x) | ((unsigned)f2bf(c.y) << 16);
  p.w = (unsigned)f2bf(c.z) | ((unsigned)f2bf(c.w) << 16);
  *(uint4*)&d[idx] = p;
}

// ---------------- NT GEMM (QKV + proj), 2-phase dbuf, as validated ----------------
template <int EPI, bool HASB>
__global__ __launch_bounds__(256) void gemm2(
    const u16* __restrict__ A, int lda, long sA,
    const u16* __restrict__ Bm, int ldb, long sB,
    void* __restrict__ O0, int ldo, long sO,
    void* __restrict__ O1, void* __restrict__ O2,
    const float* __restrict__ b0, const float* __restrict__ b1, const float* __restrict__ b2,
    const float* __restrict__ aux, long sAux,
    float scale, int K) {
  __shared__ char lsA[32768], lsB[32768];
  int bx, by, bz;
  {
    const int nx = gridDim.x, ny = gridDim.y;
    const int lin = blockIdx.x + nx * (blockIdx.y + ny * blockIdx.z);
    const int q = (nx * ny * (int)gridDim.z) >> 3;
    const int wg = (lin & 7) * q + (lin >> 3);
    bx = wg % nx; const int t2 = wg / nx; by = t2 % ny; bz = t2 / ny;
  }
  const int tid = threadIdx.x;
  const int w = tid >> 6, l = tid & 63;
  const int wm = w >> 1, wn = w & 1;
  const int m0 = by * 128, n0 = bx * 128;
  const u16* Ab = A + (size_t)bz * sA;
  const u16* Bb = Bm + (size_t)bz * sB;

  f32x4 acc[4][4];
#pragma unroll
  for (int i = 0; i < 4; ++i)
#pragma unroll
    for (int j = 0; j < 4; ++j)
#pragma unroll
      for (int q2 = 0; q2 < 4; ++q2) acc[i][j][q2] = 0.f;

  auto stage = [&](int buf, int k0) {
#pragma unroll
    for (int s = 0; s < 4; ++s) {
      const int o = s * 4096 + tid * 16;
      const int r = o >> 7;
      const int c = ((o >> 4) & 7) ^ (r & 7);
      const int ke = c * 8;
      gload_lds16(Ab + (size_t)(m0 + r) * lda + k0 + ke, lsA + buf * 16384 + s * 4096 + w * 1024);
      gload_lds16(Bb + (size_t)(n0 + r) * ldb + k0 + ke, lsB + buf * 16384 + s * 4096 + w * 1024);
    }
  };

  const int nt = K >> 6;
  stage(0, 0);
  asm volatile("s_waitcnt vmcnt(0)" ::: "memory");
  __syncthreads();
  for (int t = 0; t < nt; ++t) {
    const int cur = t & 1;
    if (t + 1 < nt) stage(cur ^ 1, (t + 1) << 6);
#pragma unroll
    for (int kk = 0; kk < 2; ++kk) {
      bf16x8 aF[4], bF[4];
#pragma unroll
      for (int mi = 0; mi < 4; ++mi) {
        const int r = wm * 64 + mi * 16 + (l & 15);
        const int cc = (kk * 4 + (l >> 4)) ^ (r & 7);
        aF[mi] = *(const bf16x8*)(lsA + cur * 16384 + r * 128 + cc * 16);
      }
#pragma unroll
      for (int ni = 0; ni < 4; ++ni) {
        const int r = wn * 64 + ni * 16 + (l & 15);
        const int cc = (kk * 4 + (l >> 4)) ^ (r & 7);
        bF[ni] = *(const bf16x8*)(lsB + cur * 16384 + r * 128 + cc * 16);
      }
#pragma unroll
      for (int mi = 0; mi < 4; ++mi)
#pragma unroll
        for (int ni = 0; ni < 4; ++ni)
          acc[mi][ni] = __builtin_amdgcn_mfma_f32_16x16x32_bf16(aF[mi], bF[ni], acc[mi][ni], 0, 0, 0);
    }
    asm volatile("s_waitcnt vmcnt(0)" ::: "memory");
    __syncthreads();
  }

  const int lc = l & 15;
  const int lr4 = (l >> 4) * 4;   // C/D: col=lane&15, row=(lane>>4)*4+reg

  if (EPI == 5) {
    const int sel = m0 >> 8;   // 0:Q 1:K 2:V
    const float* bs = sel == 0 ? b0 : sel == 1 ? b1 : b2;
#pragma unroll
    for (int mi = 0; mi < 4; ++mi) {
      const int mg = m0 + wm * 64 + mi * 16 + lr4;
      const int mloc = mg & 255;
      const float4 bv = *(const float4*)&bs[mloc];
      float bb4[4] = {bv.x, bv.y, bv.z, bv.w};
#pragma unroll
      for (int ni = 0; ni < 4; ++ni) {
        const int n = n0 + wn * 64 + ni * 16 + lc;
        if (sel == 2) {
          u16* V = (u16*)O2 + (size_t)bz * sO;
#pragma unroll
          for (int q2 = 0; q2 < 4; ++q2) V[(size_t)(mloc + q2) * HW + n] = f2bf(acc[mi][ni][q2] + bb4[q2]);
        } else {
          u16* Oq = (u16*)(sel == 0 ? O0 : O1) + (size_t)bz * sO;
          u16x4 pk;
#pragma unroll
          for (int q2 = 0; q2 < 4; ++q2) pk[q2] = f2bf(acc[mi][ni][q2] + bb4[q2]);
          *(u16x4*)&Oq[(size_t)n * CCH + mloc] = pk;
        }
      }
    }
  } else {   // EPI == 2: fp32 out + bias + residual
    float* O = (float*)O0 + (size_t)bz * sO;
    const float* R = aux + (size_t)bz * sAux;
#pragma unroll
    for (int mi = 0; mi < 4; ++mi) {
      const int mb = m0 + wm * 64 + mi * 16 + lr4;
      float bb4[4] = {0.f, 0.f, 0.f, 0.f};
      if (HASB) {
        const float4 bv = *(const float4*)&b0[mb];
        bb4[0] = bv.x; bb4[1] = bv.y; bb4[2] = bv.z; bb4[3] = bv.w;
      }
#pragma unroll
      for (int ni = 0; ni < 4; ++ni) {
        const int n = n0 + wn * 64 + ni * 16 + lc;
#pragma unroll
        for (int q2 = 0; q2 < 4; ++q2)
          O[(size_t)(mb + q2) * ldo + n] = acc[mi][ni][q2] * scale + bb4[q2] + R[(size_t)(mb + q2) * ldo + n];
      }
    }
  }
}

// ---------------- fused flash attention ----------------
// Grid: 256 blocks. bid&7 -> (b, jh); bid>>3 -> i-tile (128 rows).
// Block: 4 waves x 32 i-rows. Q in regs. K/V tiles (KVBLK=64) dbuf in LDS.
// S^T = mfma(K, Q) -> exp(s/16-8) -> P relayout via per-wave LDS -> PV mfma(P, V).
// Outputs: Opart[jh][b*4096+i][256] f32, Rpart[jh][b*4096+i] f32 (row sums).
__global__ __launch_bounds__(256, 1) void attn_fused(
    const u16* __restrict__ Qt, const u16* __restrict__ Kt, const u16* __restrict__ Vv,
    float* __restrict__ Opart, float* __restrict__ Rpart) {
  __shared__ __attribute__((aligned(16))) char lds[2][65536];   // per buf: K 32KB | V 32KB
  __shared__ __attribute__((aligned(16))) unsigned P_lds[8][16][20];  // [wave*2+bi][i=base][j-pair dword], padded
  const int bid = blockIdx.x;
  const int g8 = bid & 7, it = bid >> 3;
  const int b = g8 >> 1, jh = g8 & 1;
  const int tid = threadIdx.x, w = tid >> 6, l = tid & 63;
  const int g = l >> 4, base = l & 15;
  const u16* Qb = Qt + (size_t)b * HW * CCH;
  const u16* Kb = Kt + (size_t)b * HW * CCH;
  const u16* Vb = Vv + (size_t)b * CCH * HW;
  const int iw0 = it * 128 + w * 32;

  // Q fragments: q[bi][kc], row = iw0 + bi*16 + base, k = kc*32 + g*8 + e
  bf16x8 q[2][8];
#pragma unroll
  for (int bi = 0; bi < 2; ++bi)
#pragma unroll
    for (int kc = 0; kc < 8; ++kc)
      q[bi][kc] = *(const bf16x8*)&Qb[(size_t)(iw0 + bi * 16 + base) * CCH + kc * 32 + g * 8];

  f32x4 oacc[2][16];
#pragma unroll
  for (int bi = 0; bi < 2; ++bi)
#pragma unroll
    for (int nc = 0; nc < 16; ++nc)
#pragma unroll
      for (int r = 0; r < 4; ++r) oacc[bi][nc][r] = 0.f;
  float rsum[2] = {0.f, 0.f};

  auto stage = [&](int buf, int j0) {
    char* Kl = lds[buf];
    char* Vl = lds[buf] + 32768;
#pragma unroll
    for (int s = 0; s < 8; ++s) {
      const int i = w * 8 + s;
      // K-tile [64 rows][32 chunks of 16B], source-swizzled: phys c5 holds logical c5^(row&7)
      const int row = i * 2 + (l >> 5);
      const int c5 = l & 31;
      gload_lds16(Kb + (size_t)(j0 + row) * CCH + ((c5 ^ (row & 7)) * 8), Kl + i * 1024);
      // V-tile slot (gi, cc) <- V[cc][j0 + gi*8 .. +7]
      const int gi = i >> 2, cc = (i & 3) * 64 + l;
      gload_lds16(Vb + (size_t)cc * HW + j0 + gi * 8, Vl + i * 1024);
    }
  };

  const int j0base = jh * 2048;
  const int NT = 32;   // 2048 / 64
  stage(0, j0base);
  asm volatile("s_waitcnt vmcnt(0)" ::: "memory");
  __syncthreads();

  for (int t = 0; t < NT; ++t) {
    const int cur = t & 1;
    if (t + 1 < NT) stage(cur ^ 1, j0base + (t + 1) * 64);
    const char* Kl = lds[cur];
    const char* Vl = lds[cur] + 32768;
#pragma unroll
    for (int h = 0; h < 2; ++h) {
      // ---- S^T[j 32][i 32] over K=256 ----
      f32x4 sacc[2][2];
#pragma unroll
      for (int mj = 0; mj < 2; ++mj)
#pragma unroll
        for (int bi = 0; bi < 2; ++bi)
#pragma unroll
          for (int r = 0; r < 4; ++r) sacc[mj][bi][r] = 0.f;
#pragma unroll
      for (int kc = 0; kc < 8; ++kc) {
        bf16x8 kf[2];
#pragma unroll
        for (int mj = 0; mj < 2; ++mj) {
          const int row = h * 32 + mj * 16 + base;
          const int c5 = (kc * 4 + g) ^ (row & 7);
          kf[mj] = *(const bf16x8*)(Kl + row * 512 + c5 * 16);
        }
#pragma unroll
        for (int mj = 0; mj < 2; ++mj)
#pragma unroll
          for (int bi = 0; bi < 2; ++bi)
            sacc[mj][bi] = __builtin_amdgcn_mfma_f32_16x16x32_bf16(kf[mj], q[bi][kc], sacc[mj][bi], 0, 0, 0);
      }
      // ---- exp + pack to bf16; lane (g,base) holds P'[j = mj*16+4g+r][i = bi*16+base].
      //      Store j-pair dwords (j = 2*jp+{0,1}, jp = mj*8+g*2+pr) to per-wave LDS. ----
#pragma unroll
      for (int bi = 0; bi < 2; ++bi)
#pragma unroll
        for (int mj = 0; mj < 2; ++mj) {
          const float p0 = __expf(sacc[mj][bi][0] * 0.0625f - 8.0f);
          const float p1 = __expf(sacc[mj][bi][1] * 0.0625f - 8.0f);
          const float p2 = __expf(sacc[mj][bi][2] * 0.0625f - 8.0f);
          const float p3 = __expf(sacc[mj][bi][3] * 0.0625f - 8.0f);
          const u16 e0 = f2bf(p0), e1 = f2bf(p1), e2 = f2bf(p2), e3 = f2bf(p3);
          rsum[bi] += (bf2f(e0) + bf2f(e1)) + (bf2f(e2) + bf2f(e3));
          P_lds[w * 2 + bi][base][mj * 8 + g * 2 + 0] = (unsigned)e0 | ((unsigned)e1 << 16);
          P_lds[w * 2 + bi][base][mj * 8 + g * 2 + 1] = (unsigned)e2 | ((unsigned)e3 << 16);
        }
      asm volatile("s_waitcnt lgkmcnt(0)" ::: "memory");
      __builtin_amdgcn_sched_barrier(0);
      // ---- A-frags: lane (g,base) reads P[i = bi*16+base][j = g*8 .. g*8+7] ----
      bf16x8 af[2];
#pragma unroll
      for (int bi = 0; bi < 2; ++bi)
        af[bi] = *(const bf16x8*)&P_lds[w * 2 + bi][base][g * 4];
      // ---- PV: O[i][c] += P.V over this 32-j chunk ----
#pragma unroll
      for (int nc = 0; nc < 16; ++nc) {
        const bf16x8 vf = *(const bf16x8*)(Vl + (h * 4 + g) * 4096 + (nc * 16 + base) * 16);
#pragma unroll
        for (int bi = 0; bi < 2; ++bi)
          oacc[bi][nc] = __builtin_amdgcn_mfma_f32_16x16x32_bf16(af[bi], vf, oacc[bi][nc], 0, 0, 0);
      }
    }
    asm volatile("s_waitcnt vmcnt(0)" ::: "memory");
    __syncthreads();
  }

  // ---- epilogue: row-sum partials + O partials (f32) ----
  rsum[0] += __shfl_xor(rsum[0], 16); rsum[0] += __shfl_xor(rsum[0], 32);
  rsum[1] += __shfl_xor(rsum[1], 16); rsum[1] += __shfl_xor(rsum[1], 32);
  if (l < 16) {
    Rpart[(size_t)jh * 16384 + b * HW + iw0 + 0 * 16 + l] = rsum[0];
    Rpart[(size_t)jh * 16384 + b * HW + iw0 + 1 * 16 + l] = rsum[1];
  }
  float* Op = Opart + (size_t)jh * 16384 * CCH + (size_t)b * HW * CCH;
#pragma unroll
  for (int bi = 0; bi < 2; ++bi)
#pragma unroll
    for (int nc = 0; nc < 16; ++nc) {
      const int c = nc * 16 + base;
#pragma unroll
      for (int r = 0; r < 4; ++r) {
        const int row = iw0 + bi * 16 + g * 4 + r;
        Op[(size_t)row * CCH + c] = oacc[bi][nc][r];
      }
    }
}

// ---------------- combine: Ot = bf16((O0+O1) / (r0+r1)) ----------------
__global__ __launch_bounds__(256) void attn_combine(const float* __restrict__ Op,
                                                    const float* __restrict__ Rp,
                                                    u16* __restrict__ Ot) {
  const int idx = blockIdx.x * 256 + threadIdx.x;   // 1M threads
  const int row = idx >> 6;                         // b*4096 + i
  const int c4 = (idx & 63) * 4;
  const float4 o0 = *(const float4*)&Op[(size_t)row * CCH + c4];
  const float4 o1 = *(const float4*)&Op[(size_t)16384 * CCH + (size_t)row * CCH + c4];
  const float inv = 1.0f / (Rp[row] + Rp[16384 + row]);
  u16x4 r;
  r[0] = f2bf((o0.x + o1.x) * inv);
  r[1] = f2bf((o0.y + o1.y) * inv);
  r[2] = f2bf((o0.z + o1.z) * inv);
  r[3] = f2bf((o0.w + o1.w) * inv);
  *(u16x4*)&Ot[(size_t)row * CCH + c4] = r;
}

extern "C" void kernel_launch(void* const* d_in, const int* in_sizes, int n_in,
                              void* d_out, int out_size, void* d_ws, size_t ws_size,
                              hipStream_t stream) {
  const float* x   = (const float*)d_in[0];
  const float* gsc = (const float*)d_in[1];
  const float* gbi = (const float*)d_in[2];
  const float* wq  = (const float*)d_in[3];
  const float* bq  = (const float*)d_in[4];
  const float* wk  = (const float*)d_in[5];
  const float* bk  = (const float*)d_in[6];
  const float* wv  = (const float*)d_in[7];
  const float* bv  = (const float*)d_in[8];
  const float* wp  = (const float*)d_in[9];
  const float* bp  = (const float*)d_in[10];
  float* out = (float*)d_out;

  char* ws = (char*)d_ws;
  size_t off = 0;
  auto alloc = [&](size_t bytes) {
    size_t o = off; off = (off + bytes + 255) & ~(size_t)255; return o;
  };
  const size_t szMat = (size_t)NBATCH * HW * CCH * 2;   // 8.4MB
  u16* W      = (u16*)(ws + alloc(4 * 65536 * 2));
  float* pgn  = (float*)(ws + alloc(16 * 32 * 2 * 4));
  float2* st  = (float2*)(ws + alloc(16 * 8));
  u16* Ht = (u16*)(ws + alloc(szMat));   // [b][i][c]
  u16* Qt = (u16*)(ws + alloc(szMat));   // [b][i][c]
  u16* Kt = (u16*)(ws + alloc(szMat));   // [b][j][c]
  u16* Vv = (u16*)(ws + alloc(szMat));   // [b][c][j]
  u16* Ot = (u16*)(ws + alloc(szMat));   // [b][i][c]
  float* Opart = (float*)(ws + alloc((size_t)2 * 16384 * CCH * 4));  // 33.5MB
  float* Rpart = (float*)(ws + alloc((size_t)2 * 16384 * 4));        // 128KB

  const long sM = (long)HW * CCH;

  wcast<<<dim3(32, 4), 256, 0, stream>>>(wq, wk, wv, wp, W);
  gn_partial<<<dim3(32, 16), 256, 0, stream>>>(x, pgn);
  gn_finalize<<<1, 64, 0, stream>>>(pgn, st);
  norm_tr<<<dim3(HW / 64, CCH / 64, NBATCH), 256, 0, stream>>>(x, st, gsc, gbi, Ht);

  // fused QKV: A = [Wq;Wk;Wv] (768x256), B = Ht -> Qt [i][c], Kt [j][c], Vv [c][j]
  gemm2<5, true><<<dim3(32, 6, NBATCH), 256, 0, stream>>>(
      W, 256, 0, Ht, 256, sM, Qt, 256, sM, Kt, Vv, bq, bk, bv, nullptr, 0, 1.f, 256);

  // fused attention
  attn_fused<<<256, 256, 0, stream>>>(Qt, Kt, Vv, Opart, Rpart);
  attn_combine<<<4096, 256, 0, stream>>>(Opart, Rpart, Ot);

  // out[c][i] = Wp . Ot^T + bp + x
  gemm2<2, true><<<dim3(32, 2, NBATCH), 256, 0, stream>>>(
      W + 3 * 65536, 256, 0, Ot, 256, sM, out, HW, (long)CCH * HW, nullptr, nullptr,
      bp, nullptr, nullptr, x, (long)CCH * HW, 1.f, 256);
}

// Round 5
// 156.879 us; speedup vs baseline: 1.4149x; 1.2650x over previous
//
#include <hip/hip_runtime.h>

// AttnBlock: GroupNorm(4) -> fused qkv 1x1conv -> FUSED flash attention
//            (S^T via mfma(K,Q), exp(s/16-8), P relayout via per-wave LDS, PV)
//            -> combine (j-split merge + 1/l scale) -> proj 1x1conv + residual
// bf16 MFMA 16x16x32 everywhere, fp32 accumulate.
// attn_fused: 512 threads (8 waves x 16 i-rows) -> 2 waves/SIMD; padded V banks.

#define HW 4096
#define CCH 256
#define NBATCH 4
#define GN_N (64 * HW)

typedef unsigned short u16;
typedef __attribute__((ext_vector_type(8))) short bf16x8;
typedef __attribute__((ext_vector_type(4))) float f32x4;
typedef __attribute__((ext_vector_type(4))) u16 u16x4;

__device__ __forceinline__ u16 f2bf(float f) {
  unsigned u = __float_as_uint(f);
  u += 0x7fffu + ((u >> 16) & 1u);   // round-to-nearest-even
  return (u16)(u >> 16);
}
__device__ __forceinline__ float bf2f(u16 h) { return __uint_as_float(((unsigned)h) << 16); }

__device__ __forceinline__ void gload_lds16(const void* g, void* l) {
  __builtin_amdgcn_global_load_lds(
      (const __attribute__((address_space(1))) unsigned*)g,
      (__attribute__((address_space(3))) unsigned*)l, 16, 0, 0);
}

// ---------------- GroupNorm stats ----------------
__global__ __launch_bounds__(256) void gn_partial(const float* __restrict__ x,
                                                  float* __restrict__ part) {
  const int bg = blockIdx.y, blk = blockIdx.x, tid = threadIdx.x;
  const float4* X = (const float4*)(x + (size_t)bg * GN_N);
  float s = 0.f, ss = 0.f;
#pragma unroll
  for (int u = 0; u < 8; ++u) {
    float4 v = X[blk * 2048 + u * 256 + tid];
    s += v.x + v.y + v.z + v.w;
    ss += v.x * v.x + v.y * v.y + v.z * v.z + v.w * v.w;
  }
  for (int off = 32; off; off >>= 1) { s += __shfl_xor(s, off); ss += __shfl_xor(ss, off); }
  __shared__ float rs[4], rss[4];
  const int w = tid >> 6;
  if ((tid & 63) == 0) { rs[w] = s; rss[w] = ss; }
  __syncthreads();
  if (tid == 0) {
    part[(bg * 32 + blk) * 2 + 0] = rs[0] + rs[1] + rs[2] + rs[3];
    part[(bg * 32 + blk) * 2 + 1] = rss[0] + rss[1] + rss[2] + rss[3];
  }
}

__global__ void gn_finalize(const float* __restrict__ part, float2* __restrict__ stats) {
  const int t = threadIdx.x;
  if (t < 16) {
    float s = 0.f, ss = 0.f;
    for (int u = 0; u < 32; ++u) { s += part[(t * 32 + u) * 2]; ss += part[(t * 32 + u) * 2 + 1]; }
    const float mean = s * (1.0f / GN_N);
    const float var = ss * (1.0f / GN_N) - mean * mean;
    stats[t] = make_float2(mean, rsqrtf(var + 1e-6f));
  }
}

// ---------------- normalize + transpose -> Ht[b][i][c] bf16 ----------------
__global__ __launch_bounds__(256) void norm_tr(const float* __restrict__ x,
                                               const float2* __restrict__ stats,
                                               const float* __restrict__ gsc,
                                               const float* __restrict__ gbi,
                                               u16* __restrict__ Ht) {
  __shared__ u16 T[64][72];
  const int i0 = blockIdx.x * 64, c0 = blockIdx.y * 64, b = blockIdx.z;
  const int tid = threadIdx.x;
  const int cl = tid >> 4;
  const int il4 = (tid & 15) * 4;
#pragma unroll
  for (int it = 0; it < 4; ++it) {
    const int c = c0 + it * 16 + cl;
    const float2 st = stats[b * 4 + (c >> 6)];
    const float sc = gsc[c] * st.y;
    const float bi = gbi[c] - st.x * sc;
    const float4 v = *(const float4*)&x[((size_t)(b * CCH + c)) * HW + i0 + il4];
    T[il4 + 0][it * 16 + cl] = f2bf(v.x * sc + bi);
    T[il4 + 1][it * 16 + cl] = f2bf(v.y * sc + bi);
    T[il4 + 2][it * 16 + cl] = f2bf(v.z * sc + bi);
    T[il4 + 3][it * 16 + cl] = f2bf(v.w * sc + bi);
  }
  __syncthreads();
  const int il = tid >> 2, cs = (tid & 3) * 16;
  const uint4 a = *(const uint4*)&T[il][cs];
  const uint4 b2 = *(const uint4*)&T[il][cs + 8];
  const size_t o = ((size_t)b * HW + i0 + il) * CCH + c0 + cs;
  *(uint4*)&Ht[o] = a;
  *(uint4*)&Ht[o + 8] = b2;
}

// ---------------- cast weights fp32 -> bf16 ----------------
__global__ __launch_bounds__(256) void wcast(const float* __restrict__ w0, const float* __restrict__ w1,
                                             const float* __restrict__ w2, const float* __restrict__ w3,
                                             u16* __restrict__ dst) {
  const float* src = blockIdx.y == 0 ? w0 : blockIdx.y == 1 ? w1 : blockIdx.y == 2 ? w2 : w3;
  u16* d = dst + (size_t)blockIdx.y * 65536;
  const int idx = (blockIdx.x * 256 + threadIdx.x) * 8;
  const float4 a = *(const float4*)&src[idx];
  const float4 c = *(const float4*)&src[idx + 4];
  uint4 p;
  p.x = (unsigned)f2bf(a.x) | ((unsigned)f2bf(a.y) << 16);
  p.y = (unsigned)f2bf(a.z) | ((unsigned)f2bf(a.w) << 16);
  p.z = (unsigned)f2bf(c.x) | ((unsigned)f2bf(c.y) << 16);
  p.w = (unsigned)f2bf(c.z) | ((unsigned)f2bf(c.w) << 16);
  *(uint4*)&d[idx] = p;
}

// ---------------- NT GEMM (QKV + proj), 2-phase dbuf, as validated ----------------
template <int EPI, bool HASB>
__global__ __launch_bounds__(256) void gemm2(
    const u16* __restrict__ A, int lda, long sA,
    const u16* __restrict__ Bm, int ldb, long sB,
    void* __restrict__ O0, int ldo, long sO,
    void* __restrict__ O1, void* __restrict__ O2,
    const float* __restrict__ b0, const float* __restrict__ b1, const float* __restrict__ b2,
    const float* __restrict__ aux, long sAux,
    float scale, int K) {
  __shared__ char lsA[32768], lsB[32768];
  int bx, by, bz;
  {
    const int nx = gridDim.x, ny = gridDim.y;
    const int lin = blockIdx.x + nx * (blockIdx.y + ny * blockIdx.z);
    const int q = (nx * ny * (int)gridDim.z) >> 3;
    const int wg = (lin & 7) * q + (lin >> 3);
    bx = wg % nx; const int t2 = wg / nx; by = t2 % ny; bz = t2 / ny;
  }
  const int tid = threadIdx.x;
  const int w = tid >> 6, l = tid & 63;
  const int wm = w >> 1, wn = w & 1;
  const int m0 = by * 128, n0 = bx * 128;
  const u16* Ab = A + (size_t)bz * sA;
  const u16* Bb = Bm + (size_t)bz * sB;

  f32x4 acc[4][4];
#pragma unroll
  for (int i = 0; i < 4; ++i)
#pragma unroll
    for (int j = 0; j < 4; ++j)
#pragma unroll
      for (int q2 = 0; q2 < 4; ++q2) acc[i][j][q2] = 0.f;

  auto stage = [&](int buf, int k0) {
#pragma unroll
    for (int s = 0; s < 4; ++s) {
      const int o = s * 4096 + tid * 16;
      const int r = o >> 7;
      const int c = ((o >> 4) & 7) ^ (r & 7);
      const int ke = c * 8;
      gload_lds16(Ab + (size_t)(m0 + r) * lda + k0 + ke, lsA + buf * 16384 + s * 4096 + w * 1024);
      gload_lds16(Bb + (size_t)(n0 + r) * ldb + k0 + ke, lsB + buf * 16384 + s * 4096 + w * 1024);
    }
  };

  const int nt = K >> 6;
  stage(0, 0);
  asm volatile("s_waitcnt vmcnt(0)" ::: "memory");
  __syncthreads();
  for (int t = 0; t < nt; ++t) {
    const int cur = t & 1;
    if (t + 1 < nt) stage(cur ^ 1, (t + 1) << 6);
#pragma unroll
    for (int kk = 0; kk < 2; ++kk) {
      bf16x8 aF[4], bF[4];
#pragma unroll
      for (int mi = 0; mi < 4; ++mi) {
        const int r = wm * 64 + mi * 16 + (l & 15);
        const int cc = (kk * 4 + (l >> 4)) ^ (r & 7);
        aF[mi] = *(const bf16x8*)(lsA + cur * 16384 + r * 128 + cc * 16);
      }
#pragma unroll
      for (int ni = 0; ni < 4; ++ni) {
        const int r = wn * 64 + ni * 16 + (l & 15);
        const int cc = (kk * 4 + (l >> 4)) ^ (r & 7);
        bF[ni] = *(const bf16x8*)(lsB + cur * 16384 + r * 128 + cc * 16);
      }
#pragma unroll
      for (int mi = 0; mi < 4; ++mi)
#pragma unroll
        for (int ni = 0; ni < 4; ++ni)
          acc[mi][ni] = __builtin_amdgcn_mfma_f32_16x16x32_bf16(aF[mi], bF[ni], acc[mi][ni], 0, 0, 0);
    }
    asm volatile("s_waitcnt vmcnt(0)" ::: "memory");
    __syncthreads();
  }

  const int lc = l & 15;
  const int lr4 = (l >> 4) * 4;   // C/D: col=lane&15, row=(lane>>4)*4+reg

  if (EPI == 5) {
    const int sel = m0 >> 8;   // 0:Q 1:K 2:V
    const float* bs = sel == 0 ? b0 : sel == 1 ? b1 : b2;
#pragma unroll
    for (int mi = 0; mi < 4; ++mi) {
      const int mg = m0 + wm * 64 + mi * 16 + lr4;
      const int mloc = mg & 255;
      const float4 bv = *(const float4*)&bs[mloc];
      float bb4[4] = {bv.x, bv.y, bv.z, bv.w};
#pragma unroll
      for (int ni = 0; ni < 4; ++ni) {
        const int n = n0 + wn * 64 + ni * 16 + lc;
        if (sel == 2) {
          u16* V = (u16*)O2 + (size_t)bz * sO;
#pragma unroll
          for (int q2 = 0; q2 < 4; ++q2) V[(size_t)(mloc + q2) * HW + n] = f2bf(acc[mi][ni][q2] + bb4[q2]);
        } else {
          u16* Oq = (u16*)(sel == 0 ? O0 : O1) + (size_t)bz * sO;
          u16x4 pk;
#pragma unroll
          for (int q2 = 0; q2 < 4; ++q2) pk[q2] = f2bf(acc[mi][ni][q2] + bb4[q2]);
          *(u16x4*)&Oq[(size_t)n * CCH + mloc] = pk;
        }
      }
    }
  } else {   // EPI == 2: fp32 out + bias + residual
    float* O = (float*)O0 + (size_t)bz * sO;
    const float* R = aux + (size_t)bz * sAux;
#pragma unroll
    for (int mi = 0; mi < 4; ++mi) {
      const int mb = m0 + wm * 64 + mi * 16 + lr4;
      float bb4[4] = {0.f, 0.f, 0.f, 0.f};
      if (HASB) {
        const float4 bv = *(const float4*)&b0[mb];
        bb4[0] = bv.x; bb4[1] = bv.y; bb4[2] = bv.z; bb4[3] = bv.w;
      }
#pragma unroll
      for (int ni = 0; ni < 4; ++ni) {
        const int n = n0 + wn * 64 + ni * 16 + lc;
#pragma unroll
        for (int q2 = 0; q2 < 4; ++q2)
          O[(size_t)(mb + q2) * ldo + n] = acc[mi][ni][q2] * scale + bb4[q2] + R[(size_t)(mb + q2) * ldo + n];
      }
    }
  }
}

// ---------------- fused flash attention ----------------
// Grid: 256 blocks x 512 threads (8 waves). bid&7 -> (b, jh); bid>>3 -> i-tile (128 rows).
// Each wave owns 16 i-rows. Q in regs. K/V tiles (KVBLK=64) dbuf in LDS (V jg-padded).
// S^T = mfma(K, Q) -> exp(s/16-8) -> P relayout via per-wave LDS -> PV mfma(P, V).
// Outputs: Opart[jh][b*4096+i][256] f32, Rpart[jh][b*4096+i] f32 (row sums).
#define LBUF 65664            // 32768 (K) + 8*4112 (V, padded)
__global__ __launch_bounds__(512, 2) void attn_fused(
    const u16* __restrict__ Qt, const u16* __restrict__ Kt, const u16* __restrict__ Vv,
    float* __restrict__ Opart, float* __restrict__ Rpart) {
  __shared__ __attribute__((aligned(16))) char lds[2 * LBUF];
  __shared__ __attribute__((aligned(16))) unsigned P_lds[8][16][36];  // [wave][i=base][j-pair dword], padded
  const int bid = blockIdx.x;
  const int g8 = bid & 7, it = bid >> 3;
  const int b = g8 >> 1, jh = g8 & 1;
  const int tid = threadIdx.x, w = tid >> 6, l = tid & 63;
  const int g = l >> 4, base = l & 15;
  const u16* Qb = Qt + (size_t)b * HW * CCH;
  const u16* Kb = Kt + (size_t)b * HW * CCH;
  const u16* Vb = Vv + (size_t)b * CCH * HW;
  const int iw0 = it * 128 + w * 16;

  // Q fragments: q[kc], row = iw0 + base, k = kc*32 + g*8 + e
  bf16x8 q[8];
#pragma unroll
  for (int kc = 0; kc < 8; ++kc)
    q[kc] = *(const bf16x8*)&Qb[(size_t)(iw0 + base) * CCH + kc * 32 + g * 8];

  f32x4 oacc[16];
#pragma unroll
  for (int nc = 0; nc < 16; ++nc)
#pragma unroll
    for (int r = 0; r < 4; ++r) oacc[nc][r] = 0.f;
  float rsum = 0.f;

  auto stage = [&](int buf, int j0) {
    char* Kl = lds + buf * LBUF;
    char* Vl = Kl + 32768;
#pragma unroll
    for (int s = 0; s < 8; ++s) {
      const int i = w * 8 + s;   // 0..63 (wave-uniform selector)
      if (i < 32) {
        // K-tile [64 rows][32 chunks of 16B], source-swizzled: phys c5 holds logical c5^(row&7)
        const int row = i * 2 + (l >> 5);
        const int c5 = l & 31;
        gload_lds16(Kb + (size_t)(j0 + row) * CCH + ((c5 ^ (row & 7)) * 8), Kl + i * 1024);
      } else {
        // V-tile [8 jg (stride 4112)][256 c][16B]: slot (jg, cc) <- V[cc][j0 + jg*8 .. +7]
        const int jj = i - 32;          // 0..31
        const int jg = jj >> 2;
        const int cc = (jj & 3) * 64 + l;
        gload_lds16(Vb + (size_t)cc * HW + j0 + jg * 8, Vl + jg * 4112 + (jj & 3) * 1024);
      }
    }
  };

  const int j0base = jh * 2048;
  const int NT = 32;   // 2048 / 64
  stage(0, j0base);
  asm volatile("s_waitcnt vmcnt(0)" ::: "memory");
  __syncthreads();

  for (int t = 0; t < NT; ++t) {
    const int cur = t & 1;
    if (t + 1 < NT) stage(cur ^ 1, j0base + (t + 1) * 64);
    const char* Kl = lds + cur * LBUF;
    const char* Vl = Kl + 32768;
    // ---- S^T[j 64][i 16] over K=256 ----
    f32x4 sacc[4];
#pragma unroll
    for (int mj = 0; mj < 4; ++mj)
#pragma unroll
      for (int r = 0; r < 4; ++r) sacc[mj][r] = 0.f;
#pragma unroll
    for (int kc = 0; kc < 8; ++kc) {
      bf16x8 kf[4];
#pragma unroll
      for (int mj = 0; mj < 4; ++mj) {
        const int row = mj * 16 + base;
        const int c5 = (kc * 4 + g) ^ (row & 7);
        kf[mj] = *(const bf16x8*)(Kl + row * 512 + c5 * 16);
      }
#pragma unroll
      for (int mj = 0; mj < 4; ++mj)
        sacc[mj] = __builtin_amdgcn_mfma_f32_16x16x32_bf16(kf[mj], q[kc], sacc[mj], 0, 0, 0);
    }
    // ---- exp + pack to bf16; lane (g,base) holds P'[j = mj*16+4g+r][i = base].
    //      Store j-pair dwords (jp = mj*8+g*2+pr; j = 2*jp+{0,1}) to per-wave LDS. ----
#pragma unroll
    for (int mj = 0; mj < 4; ++mj) {
      const float p0 = __expf(sacc[mj][0] * 0.0625f - 8.0f);
      const float p1 = __expf(sacc[mj][1] * 0.0625f - 8.0f);
      const float p2 = __expf(sacc[mj][2] * 0.0625f - 8.0f);
      const float p3 = __expf(sacc[mj][3] * 0.0625f - 8.0f);
      const u16 e0 = f2bf(p0), e1 = f2bf(p1), e2 = f2bf(p2), e3 = f2bf(p3);
      rsum += (bf2f(e0) + bf2f(e1)) + (bf2f(e2) + bf2f(e3));
      P_lds[w][base][mj * 8 + g * 2 + 0] = (unsigned)e0 | ((unsigned)e1 << 16);
      P_lds[w][base][mj * 8 + g * 2 + 1] = (unsigned)e2 | ((unsigned)e3 << 16);
    }
    asm volatile("s_waitcnt lgkmcnt(0)" ::: "memory");
    __builtin_amdgcn_sched_barrier(0);
    // ---- A-frags: lane (g,base) reads P[i = base][j = ks*32 + g*8 .. +7] ----
    bf16x8 af[2];
#pragma unroll
    for (int ks = 0; ks < 2; ++ks)
      af[ks] = *(const bf16x8*)&P_lds[w][base][ks * 16 + g * 4];
    // ---- PV: O[i][c] += P.V over this 64-j chunk ----
#pragma unroll
    for (int nc = 0; nc < 16; ++nc) {
#pragma unroll
      for (int ks = 0; ks < 2; ++ks) {
        const bf16x8 vf = *(const bf16x8*)(Vl + (ks * 4 + g) * 4112 + (nc * 16 + base) * 16);
        oacc[nc] = __builtin_amdgcn_mfma_f32_16x16x32_bf16(af[ks], vf, oacc[nc], 0, 0, 0);
      }
    }
    asm volatile("s_waitcnt vmcnt(0)" ::: "memory");
    __syncthreads();
  }

  // ---- epilogue: row-sum partials + O partials (f32) ----
  rsum += __shfl_xor(rsum, 16);
  rsum += __shfl_xor(rsum, 32);
  if (l < 16) Rpart[(size_t)jh * 16384 + b * HW + iw0 + l] = rsum;
  float* Op = Opart + (size_t)jh * 16384 * CCH + (size_t)b * HW * CCH;
#pragma unroll
  for (int nc = 0; nc < 16; ++nc) {
    const int c = nc * 16 + base;
#pragma unroll
    for (int r = 0; r < 4; ++r) {
      const int row = iw0 + g * 4 + r;
      Op[(size_t)row * CCH + c] = oacc[nc][r];
    }
  }
}

// ---------------- combine: Ot = bf16((O0+O1) / (r0+r1)) ----------------
__global__ __launch_bounds__(256) void attn_combine(const float* __restrict__ Op,
                                                    const float* __restrict__ Rp,
                                                    u16* __restrict__ Ot) {
  const int idx = blockIdx.x * 256 + threadIdx.x;   // 1M threads
  const int row = idx >> 6;                         // b*4096 + i
  const int c4 = (idx & 63) * 4;
  const float4 o0 = *(const float4*)&Op[(size_t)row * CCH + c4];
  const float4 o1 = *(const float4*)&Op[(size_t)16384 * CCH + (size_t)row * CCH + c4];
  const float inv = 1.0f / (Rp[row] + Rp[16384 + row]);
  u16x4 r;
  r[0] = f2bf((o0.x + o1.x) * inv);
  r[1] = f2bf((o0.y + o1.y) * inv);
  r[2] = f2bf((o0.z + o1.z) * inv);
  r[3] = f2bf((o0.w + o1.w) * inv);
  *(u16x4*)&Ot[(size_t)row * CCH + c4] = r;
}

extern "C" void kernel_launch(void* const* d_in, const int* in_sizes, int n_in,
                              void* d_out, int out_size, void* d_ws, size_t ws_size,
                              hipStream_t stream) {
  const float* x   = (const float*)d_in[0];
  const float* gsc = (const float*)d_in[1];
  const float* gbi = (const float*)d_in[2];
  const float* wq  = (const float*)d_in[3];
  const float* bq  = (const float*)d_in[4];
  const float* wk  = (const float*)d_in[5];
  const float* bk  = (const float*)d_in[6];
  const float* wv  = (const float*)d_in[7];
  const float* bv  = (const float*)d_in[8];
  const float* wp  = (const float*)d_in[9];
  const float* bp  = (const float*)d_in[10];
  float* out = (float*)d_out;

  char* ws = (char*)d_ws;
  size_t off = 0;
  auto alloc = [&](size_t bytes) {
    size_t o = off; off = (off + bytes + 255) & ~(size_t)255; return o;
  };
  const size_t szMat = (size_t)NBATCH * HW * CCH * 2;   // 8.4MB
  u16* W      = (u16*)(ws + alloc(4 * 65536 * 2));
  float* pgn  = (float*)(ws + alloc(16 * 32 * 2 * 4));
  float2* st  = (float2*)(ws + alloc(16 * 8));
  u16* Ht = (u16*)(ws + alloc(szMat));   // [b][i][c]
  u16* Qt = (u16*)(ws + alloc(szMat));   // [b][i][c]
  u16* Kt = (u16*)(ws + alloc(szMat));   // [b][j][c]
  u16* Vv = (u16*)(ws + alloc(szMat));   // [b][c][j]
  u16* Ot = (u16*)(ws + alloc(szMat));   // [b][i][c]
  float* Opart = (float*)(ws + alloc((size_t)2 * 16384 * CCH * 4));  // 33.5MB
  float* Rpart = (float*)(ws + alloc((size_t)2 * 16384 * 4));        // 128KB

  const long sM = (long)HW * CCH;

  wcast<<<dim3(32, 4), 256, 0, stream>>>(wq, wk, wv, wp, W);
  gn_partial<<<dim3(32, 16), 256, 0, stream>>>(x, pgn);
  gn_finalize<<<1, 64, 0, stream>>>(pgn, st);
  norm_tr<<<dim3(HW / 64, CCH / 64, NBATCH), 256, 0, stream>>>(x, st, gsc, gbi, Ht);

  // fused QKV: A = [Wq;Wk;Wv] (768x256), B = Ht -> Qt [i][c], Kt [j][c], Vv [c][j]
  gemm2<5, true><<<dim3(32, 6, NBATCH), 256, 0, stream>>>(
      W, 256, 0, Ht, 256, sM, Qt, 256, sM, Kt, Vv, bq, bk, bv, nullptr, 0, 1.f, 256);

  // fused attention
  attn_fused<<<256, 512, 0, stream>>>(Qt, Kt, Vv, Opart, Rpart);
  attn_combine<<<4096, 256, 0, stream>>>(Opart, Rpart, Ot);

  // out[c][i] = Wp . Ot^T + bp + x
  gemm2<2, true><<<dim3(32, 2, NBATCH), 256, 0, stream>>>(
      W + 3 * 65536, 256, 0, Ot, 256, sM, out, HW, (long)CCH * HW, nullptr, nullptr,
      bp, nullptr, nullptr, x, (long)CCH * HW, 1.f, 256);
}